// Round 3
// baseline (1940.214 us; speedup 1.0000x reference)
//
#include <hip/hip_runtime.h>

// Problem constants
#define NLAT 192      // K (latitude rings)
#define MM   192      // zonal wavenumbers kept (M = TRUNC+1)
#define LL   192      // l dimension
#define PMAX 404      // max ring length
#define NGRID 41088
#define BC   1024     // BATCH*CHAN = 16*64
#define TWO_PI_F 6.2831853071795864769f

// Smallest ring index with nonzero basis for wavenumber m.
// nlon_k = 24 + 4k (k < 96), mirrored for k >= 96; nonzero iff m <= nlon/2.
__device__ __forceinline__ int kmin_of_m(int m) {
    return (m <= 12) ? 0 : ((m - 11) >> 1);
}

// ---------------------------------------------------------------------------
// Stage 1: per-ring DFT.  re/im[m][k][bc] = 2pi * sum_p x[bc][slon+p]*basis[k][p][m]
// Grid: (bcc/128, 3 m-tiles, 192 k).  Block 512 (8 waves).  128bc x 64m tile,
// 4x4 micro (32 accs -> VGPR<=64 -> 8 waves/SIMD).
// Zero tiles (m0 > nlon/2) are written only inside the band stage2 can read.
// ---------------------------------------------------------------------------
__global__ __launch_bounds__(512, 8) void sht_stage1(
    const float* __restrict__ x,
    const float* __restrict__ cosb,
    const float* __restrict__ sinb,
    const int*   __restrict__ ring,
    float* __restrict__ ws,        // re at 0, im at MM*NLAT*bcc
    int bc0, int bcc)
{
    const int k   = blockIdx.z;
    const int m0  = blockIdx.y * 64;
    const int bct = blockIdx.x * 128;
    const int tid = threadIdx.x;
    const int tx  = tid & 31;                   // -> bc micro (4*tx + i)
    const int ty  = (tid >> 5) & 15;            // -> m  micro (4*ty + j)

    const int slon = ring[k * PMAX];
    const int nlon = ring[k * PMAX + PMAX - 1] - slon + 1;

    float* __restrict__ re_ws = ws;
    float* __restrict__ im_ws = ws + (size_t)MM * NLAT * bcc;

    if (m0 > (nlon >> 1)) {
        const int klo16 = kmin_of_m(m0) & ~15;
        if (k < klo16 || k > (NLAT - 1) - klo16) return;   // never read by stage2
        const float4 z = {0.f, 0.f, 0.f, 0.f};
#pragma unroll
        for (int j = 0; j < 4; ++j) {
            const int m = m0 + 4 * ty + j;
            const size_t base = ((size_t)m * NLAT + k) * bcc + bct + 4 * tx;
            *(float4*)&re_ws[base] = z;
            *(float4*)&im_ws[base] = z;
        }
        return;
    }

    __shared__ float xs[16][128];   // [p][bc]
    __shared__ float cs[16][64];    // [p][m]
    __shared__ float ss[16][64];

    float accr[4][4] = {{0.f}};
    float acci[4][4] = {{0.f}};

    const int xpq  = (tid & 3) * 4;             // p offset (0,4,8,12)
    const int xbl  = tid >> 2;                  // 0..127 bc lane
    const int bpl  = (tid >> 4) & 15;           // basis p row
    const int bmq  = (tid & 15) * 4;            // basis m col
    const int half = tid >> 8;                  // 0: cos, 1: sin

    for (int p0 = 0; p0 < nlon; p0 += 16) {
        {
            float4 v = {0.f, 0.f, 0.f, 0.f};
            if (p0 + xpq < nlon)   // nlon, slon multiples of 4 -> aligned
                v = *(const float4*)(x + (size_t)(bc0 + bct + xbl) * NGRID + slon + p0 + xpq);
            xs[xpq + 0][xbl] = v.x;
            xs[xpq + 1][xbl] = v.y;
            xs[xpq + 2][xbl] = v.z;
            xs[xpq + 3][xbl] = v.w;
        }
        {
            float4 b = {0.f, 0.f, 0.f, 0.f};
            if (p0 + bpl < PMAX) {
                const size_t off = ((size_t)k * PMAX + p0 + bpl) * MM + m0 + bmq;
                b = *(const float4*)((half ? sinb : cosb) + off);
            }
            if (half) *(float4*)&ss[bpl][bmq] = b;
            else      *(float4*)&cs[bpl][bmq] = b;
        }
        __syncthreads();

#pragma unroll
        for (int pp = 0; pp < 16; ++pp) {
            const float4 xa = *(const float4*)&xs[pp][4 * tx];
            const float4 cv = *(const float4*)&cs[pp][4 * ty];
            const float4 sv = *(const float4*)&ss[pp][4 * ty];
            const float xv[4] = {xa.x, xa.y, xa.z, xa.w};
            const float cw[4] = {cv.x, cv.y, cv.z, cv.w};
            const float sw[4] = {sv.x, sv.y, sv.z, sv.w};
#pragma unroll
            for (int i = 0; i < 4; ++i)
#pragma unroll
                for (int j = 0; j < 4; ++j) {
                    accr[i][j] += xv[i] * cw[j];
                    acci[i][j] += xv[i] * sw[j];
                }
        }
        __syncthreads();
    }

#pragma unroll
    for (int j = 0; j < 4; ++j) {
        const int m = m0 + 4 * ty + j;
        const size_t base = ((size_t)m * NLAT + k) * bcc + bct + 4 * tx;
        float4 r = {accr[0][j] * TWO_PI_F, accr[1][j] * TWO_PI_F,
                    accr[2][j] * TWO_PI_F, accr[3][j] * TWO_PI_F};
        float4 s = {acci[0][j] * TWO_PI_F, acci[1][j] * TWO_PI_F,
                    acci[2][j] * TWO_PI_F, acci[3][j] * TWO_PI_F};
        *(float4*)&re_ws[base] = r;
        *(float4*)&im_ws[base] = s;
    }
}

// ---------------------------------------------------------------------------
// Stage 2 (parity-folded): using weight[m][l][191-k] = (-1)^(l+m) weight[m][l][k],
//   ws2[m][l][bc] = sum_{p=klo16}^{95} weight[m][l][p] * (a_p +- a_{191-p})
// with + iff (l+m) even.  E/O rows staged in LDS, pre-swapped by m parity so
// even-j l's always read array A and odd-j l's array B (compile-time select).
// Grid: (bcc/128, 3 l-tiles, 192 m).  Block 512.  128bc x 64l tile, 4x4 micro.
// ---------------------------------------------------------------------------
__global__ __launch_bounds__(512, 8) void sht_stage2(
    const float* __restrict__ ws,
    float* __restrict__ ws2,
    const float* __restrict__ weight,
    int bcc)
{
    const int m   = blockIdx.z;
    const int l0  = blockIdx.y * 64;
    const int bct = blockIdx.x * 128;
    if (l0 + 63 < m) return;                   // weight == 0 for whole tile

    const int tid = threadIdx.x;
    const int tx  = tid & 31;                  // -> bc micro
    const int ty  = (tid >> 5) & 15;           // -> l micro

    const int klo16 = kmin_of_m(m) & ~15;
    const int pcnt  = 96 - klo16;              // pair count, multiple of 16

    const float* __restrict__ re_ws = ws;
    const float* __restrict__ im_ws = ws + (size_t)MM * NLAT * bcc;

    __shared__ float Ar[16][128];   // even-j source (re)
    __shared__ float Br[16][128];   // odd-j  source (re)
    __shared__ float Ai[16][128];
    __shared__ float Bi[16][128];
    __shared__ float wl[16][68];    // [k][l], padded (68*4 % 16 == 0)

    float accr[4][4] = {{0.f}};
    float acci[4][4] = {{0.f}};

    const bool modd = (m & 1) != 0;
    const int  srow = tid >> 5;                // 0..15 pair-row
    const int  scol = (tid & 31) * 4;          // bc col
    const int  wkk  = tid & 15;
    const int  wlw  = tid >> 4;                // 0..31

    for (int pc = 0; pc < pcnt; pc += 16) {
        const int p0 = klo16 + pc;
        {
            const size_t offa = ((size_t)m * NLAT + (p0 + srow)) * bcc + bct + scol;
            const size_t offb = ((size_t)m * NLAT + (191 - p0 - srow)) * bcc + bct + scol;
            const float4 ar = *(const float4*)&re_ws[offa];
            const float4 br = *(const float4*)&re_ws[offb];
            const float4 ai = *(const float4*)&im_ws[offa];
            const float4 bi = *(const float4*)&im_ws[offb];
            float4 er = {ar.x + br.x, ar.y + br.y, ar.z + br.z, ar.w + br.w};
            float4 od = {ar.x - br.x, ar.y - br.y, ar.z - br.z, ar.w - br.w};
            float4 ei = {ai.x + bi.x, ai.y + bi.y, ai.z + bi.z, ai.w + bi.w};
            float4 oi = {ai.x - bi.x, ai.y - bi.y, ai.z - bi.z, ai.w - bi.w};
            if (modd) { float4 t = er; er = od; od = t; t = ei; ei = oi; oi = t; }
            *(float4*)&Ar[srow][scol] = er;
            *(float4*)&Br[srow][scol] = od;
            *(float4*)&Ai[srow][scol] = ei;
            *(float4*)&Bi[srow][scol] = oi;
        }
        {
            wl[wkk][wlw]      = weight[((size_t)m * LL + l0 + wlw) * NLAT + p0 + wkk];
            wl[wkk][wlw + 32] = weight[((size_t)m * LL + l0 + wlw + 32) * NLAT + p0 + wkk];
        }
        __syncthreads();

#pragma unroll
        for (int kk = 0; kk < 16; ++kk) {
            const float4 e_r = *(const float4*)&Ar[kk][4 * tx];
            const float4 o_r = *(const float4*)&Br[kk][4 * tx];
            const float4 e_i = *(const float4*)&Ai[kk][4 * tx];
            const float4 o_i = *(const float4*)&Bi[kk][4 * tx];
            const float4 wv  = *(const float4*)&wl[kk][4 * ty];
            const float er4[4] = {e_r.x, e_r.y, e_r.z, e_r.w};
            const float or4[4] = {o_r.x, o_r.y, o_r.z, o_r.w};
            const float ei4[4] = {e_i.x, e_i.y, e_i.z, e_i.w};
            const float oi4[4] = {o_i.x, o_i.y, o_i.z, o_i.w};
#pragma unroll
            for (int i = 0; i < 4; ++i) {
                accr[i][0] += er4[i] * wv.x;   // j=0: l parity even -> A
                accr[i][1] += or4[i] * wv.y;   // j=1: odd -> B
                accr[i][2] += er4[i] * wv.z;
                accr[i][3] += or4[i] * wv.w;
                acci[i][0] += ei4[i] * wv.x;
                acci[i][1] += oi4[i] * wv.y;
                acci[i][2] += ei4[i] * wv.z;
                acci[i][3] += oi4[i] * wv.w;
            }
        }
        __syncthreads();
    }

    float* __restrict__ re2 = ws2;
    float* __restrict__ im2 = ws2 + (size_t)MM * LL * bcc;
#pragma unroll
    for (int j = 0; j < 4; ++j) {
        const int l = l0 + 4 * ty + j;
        if (l < m) continue;                   // zero region: never read
        const size_t base = ((size_t)m * LL + l) * bcc + bct + 4 * tx;
        float4 r = {accr[0][j], accr[1][j], accr[2][j], accr[3][j]};
        float4 s = {acci[0][j], acci[1][j], acci[2][j], acci[3][j]};
        *(float4*)&re2[base] = r;
        *(float4*)&im2[base] = s;
    }
}

// ---------------------------------------------------------------------------
// Transpose: out[bc][l][m][2] = {re2[m][l][bc], im2[m][l][bc]}  (0 for m > l)
// Grid: (bcc/32, 3 m-tiles of 64, 192 l).  Block 256.  LDS held transposed
// ([bc][m], pad 66) so stores read float2 at 2-way banks; global writes are
// 512 B contiguous per (bc,l).
// ---------------------------------------------------------------------------
__global__ __launch_bounds__(256) void sht_transpose(
    const float* __restrict__ ws2,
    float* __restrict__ out,
    int bc0, int bcc)
{
    const int l   = blockIdx.z;
    const int m0  = blockIdx.y * 64;
    const int bct = blockIdx.x * 32;
    const int tid = threadIdx.x;

    __shared__ float t2r[32][66];   // [bc][m]
    __shared__ float t2i[32][66];

    const bool anynz = (m0 <= l);
    if (anynz) {
        const float* __restrict__ re2 = ws2;
        const float* __restrict__ im2 = ws2 + (size_t)MM * LL * bcc;
        const int bl4 = (tid & 7) * 4;         // 8 lanes * float4 = 32 bc
        const int mr  = tid >> 3;              // 0..31
#pragma unroll
        for (int r = 0; r < 2; ++r) {
            const int row = mr + r * 32;
            const size_t off = ((size_t)(m0 + row) * LL + l) * bcc + bct + bl4;
            const float4 a = *(const float4*)&re2[off];
            const float4 b = *(const float4*)&im2[off];
            t2r[bl4 + 0][row] = a.x; t2r[bl4 + 1][row] = a.y;
            t2r[bl4 + 2][row] = a.z; t2r[bl4 + 3][row] = a.w;
            t2i[bl4 + 0][row] = b.x; t2i[bl4 + 1][row] = b.y;
            t2i[bl4 + 2][row] = b.z; t2i[bl4 + 3][row] = b.w;
        }
    }
    __syncthreads();

    const int mq  = tid & 31;                  // m pair lane (2 m per lane)
    const int bcw = tid >> 5;                  // 0..7
#pragma unroll
    for (int r = 0; r < 4; ++r) {
        const int bcl = bcw + 8 * r;
        const int bc  = bc0 + bct + bcl;
        const int m   = m0 + 2 * mq;
        float4 v = {0.f, 0.f, 0.f, 0.f};
        if (anynz) {
            const float2 rr = *(const float2*)&t2r[bcl][2 * mq];
            const float2 ii = *(const float2*)&t2i[bcl][2 * mq];
            if (m     <= l) { v.x = rr.x; v.y = ii.x; }
            if (m + 1 <= l) { v.z = rr.y; v.w = ii.y; }
        }
        const size_t o = (((size_t)bc * LL + l) * MM + m) * 2;
        *(float4*)&out[o] = v;
    }
}

// ---------------------------------------------------------------------------
extern "C" void kernel_launch(void* const* d_in, const int* in_sizes, int n_in,
                              void* d_out, int out_size, void* d_ws, size_t ws_size,
                              hipStream_t stream)
{
    const float* x      = (const float*)d_in[0];
    const float* weight = (const float*)d_in[1];
    const float* cosb   = (const float*)d_in[2];
    const float* sinb   = (const float*)d_in[3];
    const int*   ring   = (const int*)d_in[4];
    float* out = (float*)d_out;
    float* wsf = (float*)d_ws;

    // Need interm (2*M*K*bcc floats) + ws2 (2*M*L*bcc floats) per chunk.
    const size_t per_bc = 4ull * MM * NLAT * sizeof(float);
    int chunk = BC;
    while ((size_t)chunk * per_bc > ws_size && chunk > 128) chunk >>= 1;

    for (int bc0 = 0; bc0 < BC; bc0 += chunk) {
        float* ws2 = wsf + 2ull * MM * NLAT * chunk;
        dim3 grid1(chunk / 128, 3, NLAT);
        hipLaunchKernelGGL(sht_stage1, grid1, dim3(512), 0, stream,
                           x, cosb, sinb, ring, wsf, bc0, chunk);
        dim3 grid2(chunk / 128, 3, MM);
        hipLaunchKernelGGL(sht_stage2, grid2, dim3(512), 0, stream,
                           wsf, ws2, weight, chunk);
        dim3 grid3(chunk / 32, 3, LL);
        hipLaunchKernelGGL(sht_transpose, grid3, dim3(256), 0, stream,
                           ws2, out, bc0, chunk);
    }
}

// Round 6
// 1092.673 us; speedup vs baseline: 1.7757x; 1.7757x over previous
//
#include <hip/hip_runtime.h>

// Problem constants
#define NLAT 192      // K (latitude rings)
#define MM   192      // zonal wavenumbers kept (M = TRUNC+1)
#define LL   192      // l dimension
#define PMAX 404      // max ring length
#define NGRID 41088
#define BC   1024     // BATCH*CHAN = 16*64
#define TWO_PI_F 6.2831853071795864769f

// Smallest ring index with nonzero basis for wavenumber m.
// nlon_k = 24 + 4k (k < 96), mirrored for k >= 96; nonzero iff m <= nlon/2.
__device__ __forceinline__ int kmin_of_m(int m) {
    return (m <= 12) ? 0 : ((m - 11) >> 1);
}

// ---------------------------------------------------------------------------
// Stage 1: per-ring DFT.  re/im[m][k][bc] = 2pi * sum_p x[bc][slon+p]*basis[k][p][m]
// Grid: (bcc/64, 3 m-tiles, 192 k).  Block 256.  64bc x 64m tile, 4x4 micro.
// (Round-0 proven config: VGPR~40, ~62% occupancy, no spill.)
// Zero tiles (m0 > nlon/2) are written only inside the band stage2 can read.
// ---------------------------------------------------------------------------
__global__ __launch_bounds__(256) void sht_stage1(
    const float* __restrict__ x,
    const float* __restrict__ cosb,
    const float* __restrict__ sinb,
    const int*   __restrict__ ring,
    float* __restrict__ ws,        // re at 0, im at MM*NLAT*bcc
    int bc0, int bcc)
{
    const int k   = blockIdx.z;
    const int m0  = blockIdx.y * 64;
    const int bct = blockIdx.x * 64;
    const int tid = threadIdx.x;
    const int tx  = tid & 15;                   // -> bc micro (4*tx + i)
    const int ty  = tid >> 4;                   // -> m  micro (4*ty + j)

    const int slon = ring[k * PMAX];
    const int nlon = ring[k * PMAX + PMAX - 1] - slon + 1;

    float* __restrict__ re_ws = ws;
    float* __restrict__ im_ws = ws + (size_t)MM * NLAT * bcc;

    if (m0 > (nlon >> 1)) {
        const int klo16 = kmin_of_m(m0) & ~15;
        if (k < klo16 || k > (NLAT - 1) - klo16) return;   // never read by stage2
        const float4 z = {0.f, 0.f, 0.f, 0.f};
#pragma unroll
        for (int j = 0; j < 4; ++j) {
            const int m = m0 + 4 * ty + j;
            const size_t base = ((size_t)m * NLAT + k) * bcc + bct + 4 * tx;
            *(float4*)&re_ws[base] = z;
            *(float4*)&im_ws[base] = z;
        }
        return;
    }

    __shared__ float xs[16][68];   // [p][bc]  (round-0 layout)
    __shared__ float cs[16][64];   // [p][m]
    __shared__ float ss[16][64];

    float accr[4][4] = {{0.f}};
    float acci[4][4] = {{0.f}};

    for (int p0 = 0; p0 < nlon; p0 += 16) {
        {
            const int pq = (tid & 3) * 4;      // p offset within chunk
            const int bl = tid >> 2;           // 0..63 bc within tile
            float4 v = {0.f, 0.f, 0.f, 0.f};
            if (p0 + pq < nlon)                // slon/nlon multiples of 4 -> aligned
                v = *(const float4*)(x + (size_t)(bc0 + bct + bl) * NGRID + slon + p0 + pq);
            xs[pq + 0][bl] = v.x;
            xs[pq + 1][bl] = v.y;
            xs[pq + 2][bl] = v.z;
            xs[pq + 3][bl] = v.w;
        }
        {
            const int mq = (tid & 15) * 4;
            const int pl = tid >> 4;           // 0..15
            float4 c = {0.f, 0.f, 0.f, 0.f};
            float4 s = {0.f, 0.f, 0.f, 0.f};
            if (p0 + pl < PMAX) {
                const size_t off = ((size_t)k * PMAX + p0 + pl) * MM + m0 + mq;
                c = *(const float4*)(cosb + off);
                s = *(const float4*)(sinb + off);
            }
            *(float4*)&cs[pl][mq] = c;
            *(float4*)&ss[pl][mq] = s;
        }
        __syncthreads();

#pragma unroll
        for (int pp = 0; pp < 16; ++pp) {
            float xv[4], cv[4], sv[4];
            *(float4*)xv = *(const float4*)&xs[pp][4 * tx];
            *(float4*)cv = *(const float4*)&cs[pp][4 * ty];
            *(float4*)sv = *(const float4*)&ss[pp][4 * ty];
#pragma unroll
            for (int i = 0; i < 4; ++i)
#pragma unroll
                for (int j = 0; j < 4; ++j) {
                    accr[i][j] += xv[i] * cv[j];
                    acci[i][j] += xv[i] * sv[j];
                }
        }
        __syncthreads();
    }

#pragma unroll
    for (int j = 0; j < 4; ++j) {
        const int m = m0 + 4 * ty + j;
        const size_t base = ((size_t)m * NLAT + k) * bcc + bct + 4 * tx;
        float4 r = {accr[0][j] * TWO_PI_F, accr[1][j] * TWO_PI_F,
                    accr[2][j] * TWO_PI_F, accr[3][j] * TWO_PI_F};
        float4 s = {acci[0][j] * TWO_PI_F, acci[1][j] * TWO_PI_F,
                    acci[2][j] * TWO_PI_F, acci[3][j] * TWO_PI_F};
        *(float4*)&re_ws[base] = r;
        *(float4*)&im_ws[base] = s;
    }
}

// ---------------------------------------------------------------------------
// Stage 2 (parity-folded): using weight[m][l][191-k] = (-1)^(l+m) weight[m][l][k],
//   ws2[m][l][bc] = sum_{p=klo16}^{95} weight[m][l][p] * (a_p +- a_{191-p})
// with + iff (l+m) even.  E/O rows staged in LDS, pre-swapped by m parity so
// even-j l's always read array A and odd-j l's array B (compile-time select).
// Grid: (bcc/64, 3 l-tiles, 192 m).  Block 256.  64bc x 64l tile, 4x4 micro.
// No min-waves launch bound: the inner loop needs ~70 VGPRs; forcing 64
// caused catastrophic scratch spill (round-3 post-mortem).
// ---------------------------------------------------------------------------
__global__ __launch_bounds__(256) void sht_stage2(
    const float* __restrict__ ws,
    float* __restrict__ ws2,
    const float* __restrict__ weight,
    int bcc)
{
    const int m   = blockIdx.z;
    const int l0  = blockIdx.y * 64;
    const int bct = blockIdx.x * 64;
    if (l0 + 63 < m) return;                   // weight == 0 for whole tile

    const int tid = threadIdx.x;
    const int tx  = tid & 15;                  // -> bc micro
    const int ty  = tid >> 4;                  // -> l micro

    const int klo16 = kmin_of_m(m) & ~15;
    const int pcnt  = 96 - klo16;              // pair count, multiple of 16

    const float* __restrict__ re_ws = ws;
    const float* __restrict__ im_ws = ws + (size_t)MM * NLAT * bcc;

    __shared__ float Ar[16][64];    // even-parity source (re)
    __shared__ float Br[16][64];    // odd-parity  source (re)
    __shared__ float Ai[16][64];
    __shared__ float Bi[16][64];
    __shared__ float wl[16][68];    // [k][l], padded

    float accr[4][4] = {{0.f}};
    float acci[4][4] = {{0.f}};

    const bool modd = (m & 1) != 0;
    const int  srow = tid >> 4;                // 0..15 pair-row
    const int  scol = (tid & 15) * 4;          // bc col (float4)
    const int  wkk  = tid & 15;
    const int  wlw  = tid >> 4;                // 0..15

    for (int pc = 0; pc < pcnt; pc += 16) {
        const int p0 = klo16 + pc;
        {
            const size_t offa = ((size_t)m * NLAT + (p0 + srow)) * bcc + bct + scol;
            const size_t offb = ((size_t)m * NLAT + (191 - p0 - srow)) * bcc + bct + scol;
            const float4 ar = *(const float4*)&re_ws[offa];
            const float4 br = *(const float4*)&re_ws[offb];
            const float4 ai = *(const float4*)&im_ws[offa];
            const float4 bi = *(const float4*)&im_ws[offb];
            float4 er = {ar.x + br.x, ar.y + br.y, ar.z + br.z, ar.w + br.w};
            float4 od = {ar.x - br.x, ar.y - br.y, ar.z - br.z, ar.w - br.w};
            float4 ei = {ai.x + bi.x, ai.y + bi.y, ai.z + bi.z, ai.w + bi.w};
            float4 oi = {ai.x - bi.x, ai.y - bi.y, ai.z - bi.z, ai.w - bi.w};
            if (modd) { float4 t = er; er = od; od = t; t = ei; ei = oi; oi = t; }
            *(float4*)&Ar[srow][scol] = er;
            *(float4*)&Br[srow][scol] = od;
            *(float4*)&Ai[srow][scol] = ei;
            *(float4*)&Bi[srow][scol] = oi;
        }
        {
#pragma unroll
            for (int r = 0; r < 4; ++r) {
                const int lc = wlw + r * 16;
                wl[wkk][lc] = weight[((size_t)m * LL + l0 + lc) * NLAT + p0 + wkk];
            }
        }
        __syncthreads();

#pragma unroll
        for (int kk = 0; kk < 16; ++kk) {
            float er4[4], or4[4], ei4[4], oi4[4], wv[4];
            *(float4*)er4 = *(const float4*)&Ar[kk][4 * tx];
            *(float4*)or4 = *(const float4*)&Br[kk][4 * tx];
            *(float4*)ei4 = *(const float4*)&Ai[kk][4 * tx];
            *(float4*)oi4 = *(const float4*)&Bi[kk][4 * tx];
            *(float4*)wv  = *(const float4*)&wl[kk][4 * ty];
#pragma unroll
            for (int i = 0; i < 4; ++i) {
                accr[i][0] += er4[i] * wv[0];  // j=0: (l+m) even -> A
                accr[i][1] += or4[i] * wv[1];  // j=1: odd -> B
                accr[i][2] += er4[i] * wv[2];
                accr[i][3] += or4[i] * wv[3];
                acci[i][0] += ei4[i] * wv[0];
                acci[i][1] += oi4[i] * wv[1];
                acci[i][2] += ei4[i] * wv[2];
                acci[i][3] += oi4[i] * wv[3];
            }
        }
        __syncthreads();
    }

    float* __restrict__ re2 = ws2;
    float* __restrict__ im2 = ws2 + (size_t)MM * LL * bcc;
#pragma unroll
    for (int j = 0; j < 4; ++j) {
        const int l = l0 + 4 * ty + j;
        if (l < m) continue;                   // zero region: never read
        const size_t base = ((size_t)m * LL + l) * bcc + bct + 4 * tx;
        float4 r = {accr[0][j], accr[1][j], accr[2][j], accr[3][j]};
        float4 s = {acci[0][j], acci[1][j], acci[2][j], acci[3][j]};
        *(float4*)&re2[base] = r;
        *(float4*)&im2[base] = s;
    }
}

// ---------------------------------------------------------------------------
// Transpose: out[bc][l][m][2] = {re2[m][l][bc], im2[m][l][bc]}  (0 for m > l)
// Grid: (bcc/32, 3 m-tiles of 64, 192 l).  Block 256.  LDS held transposed
// ([bc][m], pad 66) so stores read float2 at 2-way banks; global writes are
// float4 (512 B contiguous per (bc,l) row).
// ---------------------------------------------------------------------------
__global__ __launch_bounds__(256) void sht_transpose(
    const float* __restrict__ ws2,
    float* __restrict__ out,
    int bc0, int bcc)
{
    const int l   = blockIdx.z;
    const int m0  = blockIdx.y * 64;
    const int bct = blockIdx.x * 32;
    const int tid = threadIdx.x;

    __shared__ float t2r[32][66];   // [bc][m]
    __shared__ float t2i[32][66];

    const bool anynz = (m0 <= l);
    if (anynz) {
        const float* __restrict__ re2 = ws2;
        const float* __restrict__ im2 = ws2 + (size_t)MM * LL * bcc;
        const int bl4 = (tid & 7) * 4;         // 8 lanes * float4 = 32 bc
        const int mr  = tid >> 3;              // 0..31
#pragma unroll
        for (int r = 0; r < 2; ++r) {
            const int row = mr + r * 32;
            const size_t off = ((size_t)(m0 + row) * LL + l) * bcc + bct + bl4;
            const float4 a = *(const float4*)&re2[off];
            const float4 b = *(const float4*)&im2[off];
            t2r[bl4 + 0][row] = a.x; t2r[bl4 + 1][row] = a.y;
            t2r[bl4 + 2][row] = a.z; t2r[bl4 + 3][row] = a.w;
            t2i[bl4 + 0][row] = b.x; t2i[bl4 + 1][row] = b.y;
            t2i[bl4 + 2][row] = b.z; t2i[bl4 + 3][row] = b.w;
        }
    }
    __syncthreads();

    const int mq  = tid & 31;                  // m pair lane (2 m per lane)
    const int bcw = tid >> 5;                  // 0..7
#pragma unroll
    for (int r = 0; r < 4; ++r) {
        const int bcl = bcw + 8 * r;
        const int bc  = bc0 + bct + bcl;
        const int m   = m0 + 2 * mq;
        float4 v = {0.f, 0.f, 0.f, 0.f};
        if (anynz) {
            const float2 rr = *(const float2*)&t2r[bcl][2 * mq];
            const float2 ii = *(const float2*)&t2i[bcl][2 * mq];
            if (m     <= l) { v.x = rr.x; v.y = ii.x; }
            if (m + 1 <= l) { v.z = rr.y; v.w = ii.y; }
        }
        const size_t o = (((size_t)bc * LL + l) * MM + m) * 2;
        *(float4*)&out[o] = v;
    }
}

// ---------------------------------------------------------------------------
extern "C" void kernel_launch(void* const* d_in, const int* in_sizes, int n_in,
                              void* d_out, int out_size, void* d_ws, size_t ws_size,
                              hipStream_t stream)
{
    const float* x      = (const float*)d_in[0];
    const float* weight = (const float*)d_in[1];
    const float* cosb   = (const float*)d_in[2];
    const float* sinb   = (const float*)d_in[3];
    const int*   ring   = (const int*)d_in[4];
    float* out = (float*)d_out;
    float* wsf = (float*)d_ws;

    // Need interm (2*M*K*bcc floats) + ws2 (2*M*L*bcc floats) per chunk.
    const size_t per_bc = 4ull * MM * NLAT * sizeof(float);
    int chunk = BC;
    while ((size_t)chunk * per_bc > ws_size && chunk > 64) chunk >>= 1;

    for (int bc0 = 0; bc0 < BC; bc0 += chunk) {
        float* ws2 = wsf + 2ull * MM * NLAT * chunk;
        dim3 grid1(chunk / 64, 3, NLAT);
        hipLaunchKernelGGL(sht_stage1, grid1, dim3(256), 0, stream,
                           x, cosb, sinb, ring, wsf, bc0, chunk);
        dim3 grid2(chunk / 64, 3, MM);
        hipLaunchKernelGGL(sht_stage2, grid2, dim3(256), 0, stream,
                           wsf, ws2, weight, chunk);
        dim3 grid3(chunk / 32, 3, LL);
        hipLaunchKernelGGL(sht_transpose, grid3, dim3(256), 0, stream,
                           ws2, out, bc0, chunk);
    }
}

// Round 7
// 1039.455 us; speedup vs baseline: 1.8666x; 1.0512x over previous
//
#include <hip/hip_runtime.h>

// Problem constants
#define NLAT 192      // K (latitude rings)
#define MM   192      // zonal wavenumbers kept (M = TRUNC+1)
#define LL   192      // l dimension
#define PMAX 404      // max ring length
#define NGRID 41088
#define BC   1024     // BATCH*CHAN = 16*64
#define TWO_PI_F 6.2831853071795864769f

// Smallest ring index with nonzero basis for wavenumber m.
// nlon_k = 24 + 4k (k < 96), mirrored for k >= 96; nonzero iff m <= nlon/2.
__device__ __forceinline__ int kmin_of_m(int m) {
    return (m <= 12) ? 0 : ((m - 11) >> 1);
}

// ---------------------------------------------------------------------------
// Stage 1: per-ring DFT.  re/im[m][k][bc] = 2pi * sum_p x[bc][slon+p]*basis[k][p][m]
// Grid: (bcc/64, 3 m-tiles, 192 k).  Block 256.  64bc x 64m tile, 4x4 micro.
// (Proven config: VGPR~40, ~61% occupancy, 347 us.)  UNCHANGED from round 6.
// ---------------------------------------------------------------------------
__global__ __launch_bounds__(256) void sht_stage1(
    const float* __restrict__ x,
    const float* __restrict__ cosb,
    const float* __restrict__ sinb,
    const int*   __restrict__ ring,
    float* __restrict__ ws,        // re at 0, im at MM*NLAT*bcc
    int bc0, int bcc)
{
    const int k   = blockIdx.z;
    const int m0  = blockIdx.y * 64;
    const int bct = blockIdx.x * 64;
    const int tid = threadIdx.x;
    const int tx  = tid & 15;                   // -> bc micro (4*tx + i)
    const int ty  = tid >> 4;                   // -> m  micro (4*ty + j)

    const int slon = ring[k * PMAX];
    const int nlon = ring[k * PMAX + PMAX - 1] - slon + 1;

    float* __restrict__ re_ws = ws;
    float* __restrict__ im_ws = ws + (size_t)MM * NLAT * bcc;

    if (m0 > (nlon >> 1)) {
        const int klo16 = kmin_of_m(m0) & ~15;
        if (k < klo16 || k > (NLAT - 1) - klo16) return;   // never read by stage2
        const float4 z = {0.f, 0.f, 0.f, 0.f};
#pragma unroll
        for (int j = 0; j < 4; ++j) {
            const int m = m0 + 4 * ty + j;
            const size_t base = ((size_t)m * NLAT + k) * bcc + bct + 4 * tx;
            *(float4*)&re_ws[base] = z;
            *(float4*)&im_ws[base] = z;
        }
        return;
    }

    __shared__ float xs[16][68];   // [p][bc]
    __shared__ float cs[16][64];   // [p][m]
    __shared__ float ss[16][64];

    float accr[4][4] = {{0.f}};
    float acci[4][4] = {{0.f}};

    for (int p0 = 0; p0 < nlon; p0 += 16) {
        {
            const int pq = (tid & 3) * 4;      // p offset within chunk
            const int bl = tid >> 2;           // 0..63 bc within tile
            float4 v = {0.f, 0.f, 0.f, 0.f};
            if (p0 + pq < nlon)                // slon/nlon multiples of 4 -> aligned
                v = *(const float4*)(x + (size_t)(bc0 + bct + bl) * NGRID + slon + p0 + pq);
            xs[pq + 0][bl] = v.x;
            xs[pq + 1][bl] = v.y;
            xs[pq + 2][bl] = v.z;
            xs[pq + 3][bl] = v.w;
        }
        {
            const int mq = (tid & 15) * 4;
            const int pl = tid >> 4;           // 0..15
            float4 c = {0.f, 0.f, 0.f, 0.f};
            float4 s = {0.f, 0.f, 0.f, 0.f};
            if (p0 + pl < PMAX) {
                const size_t off = ((size_t)k * PMAX + p0 + pl) * MM + m0 + mq;
                c = *(const float4*)(cosb + off);
                s = *(const float4*)(sinb + off);
            }
            *(float4*)&cs[pl][mq] = c;
            *(float4*)&ss[pl][mq] = s;
        }
        __syncthreads();

#pragma unroll
        for (int pp = 0; pp < 16; ++pp) {
            float xv[4], cv[4], sv[4];
            *(float4*)xv = *(const float4*)&xs[pp][4 * tx];
            *(float4*)cv = *(const float4*)&cs[pp][4 * ty];
            *(float4*)sv = *(const float4*)&ss[pp][4 * ty];
#pragma unroll
            for (int i = 0; i < 4; ++i)
#pragma unroll
                for (int j = 0; j < 4; ++j) {
                    accr[i][j] += xv[i] * cv[j];
                    acci[i][j] += xv[i] * sv[j];
                }
        }
        __syncthreads();
    }

#pragma unroll
    for (int j = 0; j < 4; ++j) {
        const int m = m0 + 4 * ty + j;
        const size_t base = ((size_t)m * NLAT + k) * bcc + bct + 4 * tx;
        float4 r = {accr[0][j] * TWO_PI_F, accr[1][j] * TWO_PI_F,
                    accr[2][j] * TWO_PI_F, accr[3][j] * TWO_PI_F};
        float4 s = {acci[0][j] * TWO_PI_F, acci[1][j] * TWO_PI_F,
                    acci[2][j] * TWO_PI_F, acci[3][j] * TWO_PI_F};
        *(float4*)&re_ws[base] = r;
        *(float4*)&im_ws[base] = s;
    }
}

// ---------------------------------------------------------------------------
// Stage 2 (parity-folded, 128bc x 64l, 8x4 micro):
//   ws2[m][l][bc] = sum_{p=klo16}^{95} weight[m][l][p] * (a_p +- a_{191-p})
// with + iff (l+m) even.  E/O rows staged in LDS, pre-swapped by m parity so
// even-j l's read array A and odd-j l's array B (compile-time select).
// Grid: (bcc/128, 3 l-tiles, 192 m).  Block 256.
// 9 ds_read_b128 per 64 FMAs (vs 5/32 at 4x4) -> FMA/LDS pipes balanced.
// ~115 VGPR, no forced min-waves (round-3 spill lesson), no spill possible
// at 256 threads (cap 256 VGPR).
// ---------------------------------------------------------------------------
__global__ __launch_bounds__(256) void sht_stage2(
    const float* __restrict__ ws,
    float* __restrict__ ws2,
    const float* __restrict__ weight,
    int bcc)
{
    const int m   = blockIdx.z;
    const int l0  = blockIdx.y * 64;
    const int bct = blockIdx.x * 128;
    if (l0 + 63 < m) return;                   // weight == 0 for whole tile

    const int tid = threadIdx.x;
    const int tx  = tid & 15;                  // -> bc micro (4*tx, 64+4*tx)
    const int ty  = tid >> 4;                  // -> l micro (4*ty + j)

    const int klo16 = kmin_of_m(m) & ~15;
    const int pcnt  = 96 - klo16;              // pair count, multiple of 16

    const float* __restrict__ re_ws = ws;
    const float* __restrict__ im_ws = ws + (size_t)MM * NLAT * bcc;

    __shared__ float Ar[16][128];   // even-parity source (re), m-parity pre-swapped
    __shared__ float Br[16][128];   // odd-parity  source (re)
    __shared__ float Ai[16][128];
    __shared__ float Bi[16][128];
    __shared__ float wl[16][68];    // [k][l], padded

    float accr[8][4] = {{0.f}};
    float acci[8][4] = {{0.f}};

    const bool modd = (m & 1) != 0;
    const int  srow = tid >> 5;                // 0..7 pair-row (2 passes)
    const int  scol = (tid & 31) * 4;          // bc col (float4), 0..124
    const int  wkk  = tid & 15;
    const int  wlw  = tid >> 4;                // 0..15

    for (int pc = 0; pc < pcnt; pc += 16) {
        const int p0 = klo16 + pc;
#pragma unroll
        for (int pass = 0; pass < 2; ++pass) {
            const int row = srow + pass * 8;
            const size_t offa = ((size_t)m * NLAT + (p0 + row)) * bcc + bct + scol;
            const size_t offb = ((size_t)m * NLAT + (191 - p0 - row)) * bcc + bct + scol;
            const float4 ar = *(const float4*)&re_ws[offa];
            const float4 br = *(const float4*)&re_ws[offb];
            const float4 ai = *(const float4*)&im_ws[offa];
            const float4 bi = *(const float4*)&im_ws[offb];
            float4 er = {ar.x + br.x, ar.y + br.y, ar.z + br.z, ar.w + br.w};
            float4 od = {ar.x - br.x, ar.y - br.y, ar.z - br.z, ar.w - br.w};
            float4 ei = {ai.x + bi.x, ai.y + bi.y, ai.z + bi.z, ai.w + bi.w};
            float4 oi = {ai.x - bi.x, ai.y - bi.y, ai.z - bi.z, ai.w - bi.w};
            if (modd) { float4 t = er; er = od; od = t; t = ei; ei = oi; oi = t; }
            *(float4*)&Ar[row][scol] = er;
            *(float4*)&Br[row][scol] = od;
            *(float4*)&Ai[row][scol] = ei;
            *(float4*)&Bi[row][scol] = oi;
        }
        {
#pragma unroll
            for (int r = 0; r < 4; ++r) {
                const int lc = wlw + r * 16;
                wl[wkk][lc] = weight[((size_t)m * LL + l0 + lc) * NLAT + p0 + wkk];
            }
        }
        __syncthreads();

#pragma unroll
        for (int kk = 0; kk < 16; ++kk) {
            const float4 ea = *(const float4*)&Ar[kk][4 * tx];
            const float4 eb = *(const float4*)&Ar[kk][64 + 4 * tx];
            const float4 oa = *(const float4*)&Br[kk][4 * tx];
            const float4 ob = *(const float4*)&Br[kk][64 + 4 * tx];
            const float4 fa = *(const float4*)&Ai[kk][4 * tx];
            const float4 fb = *(const float4*)&Ai[kk][64 + 4 * tx];
            const float4 ga = *(const float4*)&Bi[kk][4 * tx];
            const float4 gb = *(const float4*)&Bi[kk][64 + 4 * tx];
            const float4 wv = *(const float4*)&wl[kk][4 * ty];
            const float er8[8] = {ea.x, ea.y, ea.z, ea.w, eb.x, eb.y, eb.z, eb.w};
            const float or8[8] = {oa.x, oa.y, oa.z, oa.w, ob.x, ob.y, ob.z, ob.w};
            const float ei8[8] = {fa.x, fa.y, fa.z, fa.w, fb.x, fb.y, fb.z, fb.w};
            const float oi8[8] = {ga.x, ga.y, ga.z, ga.w, gb.x, gb.y, gb.z, gb.w};
#pragma unroll
            for (int i = 0; i < 8; ++i) {
                accr[i][0] += er8[i] * wv.x;   // j=0: (l+m) even -> A
                accr[i][1] += or8[i] * wv.y;   // j=1: odd -> B
                accr[i][2] += er8[i] * wv.z;
                accr[i][3] += or8[i] * wv.w;
                acci[i][0] += ei8[i] * wv.x;
                acci[i][1] += oi8[i] * wv.y;
                acci[i][2] += ei8[i] * wv.z;
                acci[i][3] += oi8[i] * wv.w;
            }
        }
        __syncthreads();
    }

    float* __restrict__ re2 = ws2;
    float* __restrict__ im2 = ws2 + (size_t)MM * LL * bcc;
#pragma unroll
    for (int j = 0; j < 4; ++j) {
        const int l = l0 + 4 * ty + j;
        if (l < m) continue;                   // zero region: never read
        const size_t base = ((size_t)m * LL + l) * bcc + bct;
        float4 r0 = {accr[0][j], accr[1][j], accr[2][j], accr[3][j]};
        float4 r1 = {accr[4][j], accr[5][j], accr[6][j], accr[7][j]};
        float4 i0 = {acci[0][j], acci[1][j], acci[2][j], acci[3][j]};
        float4 i1 = {acci[4][j], acci[5][j], acci[6][j], acci[7][j]};
        *(float4*)&re2[base + 4 * tx]      = r0;
        *(float4*)&re2[base + 64 + 4 * tx] = r1;
        *(float4*)&im2[base + 4 * tx]      = i0;
        *(float4*)&im2[base + 64 + 4 * tx] = i1;
    }
}

// ---------------------------------------------------------------------------
// Transpose: out[bc][l][m][2] = {re2[m][l][bc], im2[m][l][bc]}  (0 for m > l)
// Grid: (bcc/64, 3 m-tiles of 64, 192 l).  Block 256.
// Reads 256-B bursts (16 lanes x float4 along bc); LDS held transposed
// ([bc][m], pad 66); writes float4 -> 512 B contiguous per (bc,l).
// ---------------------------------------------------------------------------
__global__ __launch_bounds__(256) void sht_transpose(
    const float* __restrict__ ws2,
    float* __restrict__ out,
    int bc0, int bcc)
{
    const int l   = blockIdx.z;
    const int m0  = blockIdx.y * 64;
    const int bct = blockIdx.x * 64;
    const int tid = threadIdx.x;

    __shared__ float t2r[64][66];   // [bc][m]
    __shared__ float t2i[64][66];

    const bool anynz = (m0 <= l);
    if (anynz) {
        const float* __restrict__ re2 = ws2;
        const float* __restrict__ im2 = ws2 + (size_t)MM * LL * bcc;
        const int bl4 = (tid & 15) * 4;        // 16 lanes * float4 = 64 bc
        const int mr  = tid >> 4;              // 16 m-rows per pass
#pragma unroll
        for (int r = 0; r < 4; ++r) {
            const int row = mr + r * 16;
            const size_t off = ((size_t)(m0 + row) * LL + l) * bcc + bct + bl4;
            const float4 a = *(const float4*)&re2[off];
            const float4 b = *(const float4*)&im2[off];
            t2r[bl4 + 0][row] = a.x; t2r[bl4 + 1][row] = a.y;
            t2r[bl4 + 2][row] = a.z; t2r[bl4 + 3][row] = a.w;
            t2i[bl4 + 0][row] = b.x; t2i[bl4 + 1][row] = b.y;
            t2i[bl4 + 2][row] = b.z; t2i[bl4 + 3][row] = b.w;
        }
    }
    __syncthreads();

    const int mq  = tid & 31;                  // m pair lane (2 m per lane)
    const int bcw = tid >> 5;                  // 0..7
#pragma unroll
    for (int r = 0; r < 8; ++r) {
        const int bcl = bcw + 8 * r;
        const int bc  = bc0 + bct + bcl;
        const int m   = m0 + 2 * mq;
        float4 v = {0.f, 0.f, 0.f, 0.f};
        if (anynz) {
            const float2 rr = *(const float2*)&t2r[bcl][2 * mq];
            const float2 ii = *(const float2*)&t2i[bcl][2 * mq];
            if (m     <= l) { v.x = rr.x; v.y = ii.x; }
            if (m + 1 <= l) { v.z = rr.y; v.w = ii.y; }
        }
        const size_t o = (((size_t)bc * LL + l) * MM + m) * 2;
        *(float4*)&out[o] = v;
    }
}

// ---------------------------------------------------------------------------
extern "C" void kernel_launch(void* const* d_in, const int* in_sizes, int n_in,
                              void* d_out, int out_size, void* d_ws, size_t ws_size,
                              hipStream_t stream)
{
    const float* x      = (const float*)d_in[0];
    const float* weight = (const float*)d_in[1];
    const float* cosb   = (const float*)d_in[2];
    const float* sinb   = (const float*)d_in[3];
    const int*   ring   = (const int*)d_in[4];
    float* out = (float*)d_out;
    float* wsf = (float*)d_ws;

    // Need interm (2*M*K*bcc floats) + ws2 (2*M*L*bcc floats) per chunk.
    const size_t per_bc = 4ull * MM * NLAT * sizeof(float);
    int chunk = BC;
    while ((size_t)chunk * per_bc > ws_size && chunk > 128) chunk >>= 1;

    for (int bc0 = 0; bc0 < BC; bc0 += chunk) {
        float* ws2 = wsf + 2ull * MM * NLAT * chunk;
        dim3 grid1(chunk / 64, 3, NLAT);
        hipLaunchKernelGGL(sht_stage1, grid1, dim3(256), 0, stream,
                           x, cosb, sinb, ring, wsf, bc0, chunk);
        dim3 grid2(chunk / 128, 3, MM);
        hipLaunchKernelGGL(sht_stage2, grid2, dim3(256), 0, stream,
                           wsf, ws2, weight, chunk);
        dim3 grid3(chunk / 64, 3, LL);
        hipLaunchKernelGGL(sht_transpose, grid3, dim3(256), 0, stream,
                           ws2, out, bc0, chunk);
    }
}

// Round 8
// 974.527 us; speedup vs baseline: 1.9909x; 1.0666x over previous
//
#include <hip/hip_runtime.h>

// Problem constants
#define NLAT 192      // K (latitude rings)
#define MM   192      // zonal wavenumbers kept (M = TRUNC+1)
#define LL   192      // l dimension
#define PMAX 404      // max ring length
#define NGRID 41088
#define BC   1024     // BATCH*CHAN = 16*64
#define TWO_PI_F 6.2831853071795864769f

// Smallest ring index with nonzero basis for wavenumber m.
// nlon_k = 24 + 4k (k < 96), mirrored for k >= 96; nonzero iff m <= nlon/2.
__device__ __forceinline__ int kmin_of_m(int m) {
    return (m <= 12) ? 0 : ((m - 11) >> 1);
}

// ---------------------------------------------------------------------------
// Stage 1 (p-folded real DFT):
//   cos(2pi m (n-p)/n) =  cos(2pi m p/n),  sin(2pi m (n-p)/n) = -sin(...)
//   xe[p] = x[p]+x[n-p], xo[p] = x[p]-x[n-p]  (p=0, p=n/2 self-paired)
//   re[m] = sum_{p<=n/2} xe[p]*cosb[p][m];  im[m] = sum xo[p]*sinb[p][m]
// Halves the p-extent of the proven 4x4-micro inner loop.
// Grid: (bcc/64, 3 m-tiles, 192 k).  Block 256.  64bc x 64m tile.
// ---------------------------------------------------------------------------
__global__ __launch_bounds__(256) void sht_stage1(
    const float* __restrict__ x,
    const float* __restrict__ cosb,
    const float* __restrict__ sinb,
    const int*   __restrict__ ring,
    float* __restrict__ ws,        // re at 0, im at MM*NLAT*bcc
    int bc0, int bcc)
{
    const int k   = blockIdx.z;
    const int m0  = blockIdx.y * 64;
    const int bct = blockIdx.x * 64;
    const int tid = threadIdx.x;
    const int tx  = tid & 15;                   // -> bc micro (4*tx + i)
    const int ty  = tid >> 4;                   // -> m  micro (4*ty + j)

    const int slon = ring[k * PMAX];
    const int nlon = ring[k * PMAX + PMAX - 1] - slon + 1;
    const int n2   = nlon >> 1;                 // nlon always multiple of 4

    float* __restrict__ re_ws = ws;
    float* __restrict__ im_ws = ws + (size_t)MM * NLAT * bcc;

    if (m0 > n2) {
        const int klo16 = kmin_of_m(m0) & ~15;
        if (k < klo16 || k > (NLAT - 1) - klo16) return;   // never read by stage2
        const float4 z = {0.f, 0.f, 0.f, 0.f};
#pragma unroll
        for (int j = 0; j < 4; ++j) {
            const int m = m0 + 4 * ty + j;
            const size_t base = ((size_t)m * NLAT + k) * bcc + bct + 4 * tx;
            *(float4*)&re_ws[base] = z;
            *(float4*)&im_ws[base] = z;
        }
        return;
    }

    __shared__ float xe[16][68];   // [p][bc]  even fold (feeds cos)
    __shared__ float xo[16][68];   // [p][bc]  odd  fold (feeds sin)
    __shared__ float cs[16][64];   // [p][m]
    __shared__ float ss[16][64];

    float accr[4][4] = {{0.f}};
    float acci[4][4] = {{0.f}};

    for (int p0 = 0; p0 <= n2; p0 += 16) {
        {
            const int pq = (tid & 3) * 4;      // p offset within chunk
            const int bl = tid >> 2;           // 0..63 bc within tile
            const float* xrow = x + (size_t)(bc0 + bct + bl) * NGRID + slon;
            float f[4];
            if (p0 + pq + 3 <= n2) {           // aligned interior fast path
                const float4 v = *(const float4*)(xrow + p0 + pq);
                f[0] = v.x; f[1] = v.y; f[2] = v.z; f[3] = v.w;
            } else {
#pragma unroll
                for (int j = 0; j < 4; ++j) {
                    const int p = p0 + pq + j;
                    f[j] = (p <= n2) ? xrow[p] : 0.f;
                }
            }
#pragma unroll
            for (int j = 0; j < 4; ++j) {
                const int p = p0 + pq + j;
                const float b = (p >= 1 && p < n2) ? xrow[nlon - p] : 0.f;
                xe[pq + j][bl] = f[j] + b;
                xo[pq + j][bl] = f[j] - b;
            }
        }
        {
            const int mq = (tid & 15) * 4;
            const int pl = tid >> 4;           // 0..15
            float4 c = {0.f, 0.f, 0.f, 0.f};
            float4 s = {0.f, 0.f, 0.f, 0.f};
            if (p0 + pl < PMAX) {              // p <= n2+15 <= 217 < 404 always
                const size_t off = ((size_t)k * PMAX + p0 + pl) * MM + m0 + mq;
                c = *(const float4*)(cosb + off);
                s = *(const float4*)(sinb + off);
            }
            *(float4*)&cs[pl][mq] = c;
            *(float4*)&ss[pl][mq] = s;
        }
        __syncthreads();

#pragma unroll
        for (int pp = 0; pp < 16; ++pp) {
            float ev[4], ov[4], cv[4], sv[4];
            *(float4*)ev = *(const float4*)&xe[pp][4 * tx];
            *(float4*)ov = *(const float4*)&xo[pp][4 * tx];
            *(float4*)cv = *(const float4*)&cs[pp][4 * ty];
            *(float4*)sv = *(const float4*)&ss[pp][4 * ty];
#pragma unroll
            for (int i = 0; i < 4; ++i)
#pragma unroll
                for (int j = 0; j < 4; ++j) {
                    accr[i][j] += ev[i] * cv[j];
                    acci[i][j] += ov[i] * sv[j];
                }
        }
        __syncthreads();
    }

#pragma unroll
    for (int j = 0; j < 4; ++j) {
        const int m = m0 + 4 * ty + j;
        const size_t base = ((size_t)m * NLAT + k) * bcc + bct + 4 * tx;
        float4 r = {accr[0][j] * TWO_PI_F, accr[1][j] * TWO_PI_F,
                    accr[2][j] * TWO_PI_F, accr[3][j] * TWO_PI_F};
        float4 s = {acci[0][j] * TWO_PI_F, acci[1][j] * TWO_PI_F,
                    acci[2][j] * TWO_PI_F, acci[3][j] * TWO_PI_F};
        *(float4*)&re_ws[base] = r;
        *(float4*)&im_ws[base] = s;
    }
}

// ---------------------------------------------------------------------------
// Stage 2 (parity-folded, 128bc x 64l, 8x4 micro):  UNCHANGED from round 7.
//   ws2[m][l][bc] = sum_{p=klo16}^{95} weight[m][l][p] * (a_p +- a_{191-p})
// with + iff (l+m) even.  Grid: (bcc/128, 3 l-tiles, 192 m).  Block 256.
// ---------------------------------------------------------------------------
__global__ __launch_bounds__(256) void sht_stage2(
    const float* __restrict__ ws,
    float* __restrict__ ws2,
    const float* __restrict__ weight,
    int bcc)
{
    const int m   = blockIdx.z;
    const int l0  = blockIdx.y * 64;
    const int bct = blockIdx.x * 128;
    if (l0 + 63 < m) return;                   // weight == 0 for whole tile

    const int tid = threadIdx.x;
    const int tx  = tid & 15;                  // -> bc micro (4*tx, 64+4*tx)
    const int ty  = tid >> 4;                  // -> l micro (4*ty + j)

    const int klo16 = kmin_of_m(m) & ~15;
    const int pcnt  = 96 - klo16;              // pair count, multiple of 16

    const float* __restrict__ re_ws = ws;
    const float* __restrict__ im_ws = ws + (size_t)MM * NLAT * bcc;

    __shared__ float Ar[16][128];   // even-parity source (re), m-parity pre-swapped
    __shared__ float Br[16][128];   // odd-parity  source (re)
    __shared__ float Ai[16][128];
    __shared__ float Bi[16][128];
    __shared__ float wl[16][68];    // [k][l], padded

    float accr[8][4] = {{0.f}};
    float acci[8][4] = {{0.f}};

    const bool modd = (m & 1) != 0;
    const int  srow = tid >> 5;                // 0..7 pair-row (2 passes)
    const int  scol = (tid & 31) * 4;          // bc col (float4), 0..124
    const int  wkk  = tid & 15;
    const int  wlw  = tid >> 4;                // 0..15

    for (int pc = 0; pc < pcnt; pc += 16) {
        const int p0 = klo16 + pc;
#pragma unroll
        for (int pass = 0; pass < 2; ++pass) {
            const int row = srow + pass * 8;
            const size_t offa = ((size_t)m * NLAT + (p0 + row)) * bcc + bct + scol;
            const size_t offb = ((size_t)m * NLAT + (191 - p0 - row)) * bcc + bct + scol;
            const float4 ar = *(const float4*)&re_ws[offa];
            const float4 br = *(const float4*)&re_ws[offb];
            const float4 ai = *(const float4*)&im_ws[offa];
            const float4 bi = *(const float4*)&im_ws[offb];
            float4 er = {ar.x + br.x, ar.y + br.y, ar.z + br.z, ar.w + br.w};
            float4 od = {ar.x - br.x, ar.y - br.y, ar.z - br.z, ar.w - br.w};
            float4 ei = {ai.x + bi.x, ai.y + bi.y, ai.z + bi.z, ai.w + bi.w};
            float4 oi = {ai.x - bi.x, ai.y - bi.y, ai.z - bi.z, ai.w - bi.w};
            if (modd) { float4 t = er; er = od; od = t; t = ei; ei = oi; oi = t; }
            *(float4*)&Ar[row][scol] = er;
            *(float4*)&Br[row][scol] = od;
            *(float4*)&Ai[row][scol] = ei;
            *(float4*)&Bi[row][scol] = oi;
        }
        {
#pragma unroll
            for (int r = 0; r < 4; ++r) {
                const int lc = wlw + r * 16;
                wl[wkk][lc] = weight[((size_t)m * LL + l0 + lc) * NLAT + p0 + wkk];
            }
        }
        __syncthreads();

#pragma unroll
        for (int kk = 0; kk < 16; ++kk) {
            const float4 ea = *(const float4*)&Ar[kk][4 * tx];
            const float4 eb = *(const float4*)&Ar[kk][64 + 4 * tx];
            const float4 oa = *(const float4*)&Br[kk][4 * tx];
            const float4 ob = *(const float4*)&Br[kk][64 + 4 * tx];
            const float4 fa = *(const float4*)&Ai[kk][4 * tx];
            const float4 fb = *(const float4*)&Ai[kk][64 + 4 * tx];
            const float4 ga = *(const float4*)&Bi[kk][4 * tx];
            const float4 gb = *(const float4*)&Bi[kk][64 + 4 * tx];
            const float4 wv = *(const float4*)&wl[kk][4 * ty];
            const float er8[8] = {ea.x, ea.y, ea.z, ea.w, eb.x, eb.y, eb.z, eb.w};
            const float or8[8] = {oa.x, oa.y, oa.z, oa.w, ob.x, ob.y, ob.z, ob.w};
            const float ei8[8] = {fa.x, fa.y, fa.z, fa.w, fb.x, fb.y, fb.z, fb.w};
            const float oi8[8] = {ga.x, ga.y, ga.z, ga.w, gb.x, gb.y, gb.z, gb.w};
#pragma unroll
            for (int i = 0; i < 8; ++i) {
                accr[i][0] += er8[i] * wv.x;   // j=0: (l+m) even -> A
                accr[i][1] += or8[i] * wv.y;   // j=1: odd -> B
                accr[i][2] += er8[i] * wv.z;
                accr[i][3] += or8[i] * wv.w;
                acci[i][0] += ei8[i] * wv.x;
                acci[i][1] += oi8[i] * wv.y;
                acci[i][2] += ei8[i] * wv.z;
                acci[i][3] += oi8[i] * wv.w;
            }
        }
        __syncthreads();
    }

    float* __restrict__ re2 = ws2;
    float* __restrict__ im2 = ws2 + (size_t)MM * LL * bcc;
#pragma unroll
    for (int j = 0; j < 4; ++j) {
        const int l = l0 + 4 * ty + j;
        if (l < m) continue;                   // zero region: never read
        const size_t base = ((size_t)m * LL + l) * bcc + bct;
        float4 r0 = {accr[0][j], accr[1][j], accr[2][j], accr[3][j]};
        float4 r1 = {accr[4][j], accr[5][j], accr[6][j], accr[7][j]};
        float4 i0 = {acci[0][j], acci[1][j], acci[2][j], acci[3][j]};
        float4 i1 = {acci[4][j], acci[5][j], acci[6][j], acci[7][j]};
        *(float4*)&re2[base + 4 * tx]      = r0;
        *(float4*)&re2[base + 64 + 4 * tx] = r1;
        *(float4*)&im2[base + 4 * tx]      = i0;
        *(float4*)&im2[base + 64 + 4 * tx] = i1;
    }
}

// ---------------------------------------------------------------------------
// Transpose: out[bc][l][m][2] = {re2[m][l][bc], im2[m][l][bc]}  (0 for m > l)
// UNCHANGED from round 7.  Grid: (bcc/64, 3 m-tiles of 64, 192 l).  Block 256.
// ---------------------------------------------------------------------------
__global__ __launch_bounds__(256) void sht_transpose(
    const float* __restrict__ ws2,
    float* __restrict__ out,
    int bc0, int bcc)
{
    const int l   = blockIdx.z;
    const int m0  = blockIdx.y * 64;
    const int bct = blockIdx.x * 64;
    const int tid = threadIdx.x;

    __shared__ float t2r[64][66];   // [bc][m]
    __shared__ float t2i[64][66];

    const bool anynz = (m0 <= l);
    if (anynz) {
        const float* __restrict__ re2 = ws2;
        const float* __restrict__ im2 = ws2 + (size_t)MM * LL * bcc;
        const int bl4 = (tid & 15) * 4;        // 16 lanes * float4 = 64 bc
        const int mr  = tid >> 4;              // 16 m-rows per pass
#pragma unroll
        for (int r = 0; r < 4; ++r) {
            const int row = mr + r * 16;
            const size_t off = ((size_t)(m0 + row) * LL + l) * bcc + bct + bl4;
            const float4 a = *(const float4*)&re2[off];
            const float4 b = *(const float4*)&im2[off];
            t2r[bl4 + 0][row] = a.x; t2r[bl4 + 1][row] = a.y;
            t2r[bl4 + 2][row] = a.z; t2r[bl4 + 3][row] = a.w;
            t2i[bl4 + 0][row] = b.x; t2i[bl4 + 1][row] = b.y;
            t2i[bl4 + 2][row] = b.z; t2i[bl4 + 3][row] = b.w;
        }
    }
    __syncthreads();

    const int mq  = tid & 31;                  // m pair lane (2 m per lane)
    const int bcw = tid >> 5;                  // 0..7
#pragma unroll
    for (int r = 0; r < 8; ++r) {
        const int bcl = bcw + 8 * r;
        const int bc  = bc0 + bct + bcl;
        const int m   = m0 + 2 * mq;
        float4 v = {0.f, 0.f, 0.f, 0.f};
        if (anynz) {
            const float2 rr = *(const float2*)&t2r[bcl][2 * mq];
            const float2 ii = *(const float2*)&t2i[bcl][2 * mq];
            if (m     <= l) { v.x = rr.x; v.y = ii.x; }
            if (m + 1 <= l) { v.z = rr.y; v.w = ii.y; }
        }
        const size_t o = (((size_t)bc * LL + l) * MM + m) * 2;
        *(float4*)&out[o] = v;
    }
}

// ---------------------------------------------------------------------------
extern "C" void kernel_launch(void* const* d_in, const int* in_sizes, int n_in,
                              void* d_out, int out_size, void* d_ws, size_t ws_size,
                              hipStream_t stream)
{
    const float* x      = (const float*)d_in[0];
    const float* weight = (const float*)d_in[1];
    const float* cosb   = (const float*)d_in[2];
    const float* sinb   = (const float*)d_in[3];
    const int*   ring   = (const int*)d_in[4];
    float* out = (float*)d_out;
    float* wsf = (float*)d_ws;

    // Need interm (2*M*K*bcc floats) + ws2 (2*M*L*bcc floats) per chunk.
    const size_t per_bc = 4ull * MM * NLAT * sizeof(float);
    int chunk = BC;
    while ((size_t)chunk * per_bc > ws_size && chunk > 128) chunk >>= 1;

    for (int bc0 = 0; bc0 < BC; bc0 += chunk) {
        float* ws2 = wsf + 2ull * MM * NLAT * chunk;
        dim3 grid1(chunk / 64, 3, NLAT);
        hipLaunchKernelGGL(sht_stage1, grid1, dim3(256), 0, stream,
                           x, cosb, sinb, ring, wsf, bc0, chunk);
        dim3 grid2(chunk / 128, 3, MM);
        hipLaunchKernelGGL(sht_stage2, grid2, dim3(256), 0, stream,
                           wsf, ws2, weight, chunk);
        dim3 grid3(chunk / 64, 3, LL);
        hipLaunchKernelGGL(sht_transpose, grid3, dim3(256), 0, stream,
                           ws2, out, bc0, chunk);
    }
}

// Round 9
// 910.165 us; speedup vs baseline: 2.1317x; 1.0707x over previous
//
#include <hip/hip_runtime.h>

// Problem constants
#define NLAT 192      // K (latitude rings)
#define MM   192      // zonal wavenumbers kept (M = TRUNC+1)
#define LL   192      // l dimension
#define PMAX 404      // max ring length
#define NGRID 41088
#define BC   1024     // BATCH*CHAN = 16*64
#define TWO_PI_F 6.2831853071795864769f

// Smallest ring index with nonzero basis for wavenumber m.
// nlon_k = 24 + 4k (k < 96), mirrored for k >= 96; nonzero iff m <= nlon/2.
__device__ __forceinline__ int kmin_of_m(int m) {
    return (m <= 12) ? 0 : ((m - 11) >> 1);
}

// ---------------------------------------------------------------------------
// Stage 1 (p-folded real DFT):  UNCHANGED from round 8.
//   xe[p] = x[p]+x[n-p], xo[p] = x[p]-x[n-p]
//   re[m] = sum_{p<=n/2} xe[p]*cosb[p][m];  im[m] = sum xo[p]*sinb[p][m]
// Grid: (bcc/64, 3 m-tiles, 192 k).  Block 256.  64bc x 64m tile, 4x4 micro.
// ---------------------------------------------------------------------------
__global__ __launch_bounds__(256) void sht_stage1(
    const float* __restrict__ x,
    const float* __restrict__ cosb,
    const float* __restrict__ sinb,
    const int*   __restrict__ ring,
    float* __restrict__ ws,        // re at 0, im at MM*NLAT*bcc
    int bc0, int bcc)
{
    const int k   = blockIdx.z;
    const int m0  = blockIdx.y * 64;
    const int bct = blockIdx.x * 64;
    const int tid = threadIdx.x;
    const int tx  = tid & 15;                   // -> bc micro (4*tx + i)
    const int ty  = tid >> 4;                   // -> m  micro (4*ty + j)

    const int slon = ring[k * PMAX];
    const int nlon = ring[k * PMAX + PMAX - 1] - slon + 1;
    const int n2   = nlon >> 1;                 // nlon always multiple of 4

    float* __restrict__ re_ws = ws;
    float* __restrict__ im_ws = ws + (size_t)MM * NLAT * bcc;

    if (m0 > n2) {
        const int klo16 = kmin_of_m(m0) & ~15;
        if (k < klo16 || k > (NLAT - 1) - klo16) return;   // never read by stage2
        const float4 z = {0.f, 0.f, 0.f, 0.f};
#pragma unroll
        for (int j = 0; j < 4; ++j) {
            const int m = m0 + 4 * ty + j;
            const size_t base = ((size_t)m * NLAT + k) * bcc + bct + 4 * tx;
            *(float4*)&re_ws[base] = z;
            *(float4*)&im_ws[base] = z;
        }
        return;
    }

    __shared__ float xe[16][68];   // [p][bc]  even fold (feeds cos)
    __shared__ float xo[16][68];   // [p][bc]  odd  fold (feeds sin)
    __shared__ float cs[16][64];   // [p][m]
    __shared__ float ss[16][64];

    float accr[4][4] = {{0.f}};
    float acci[4][4] = {{0.f}};

    for (int p0 = 0; p0 <= n2; p0 += 16) {
        {
            const int pq = (tid & 3) * 4;      // p offset within chunk
            const int bl = tid >> 2;           // 0..63 bc within tile
            const float* xrow = x + (size_t)(bc0 + bct + bl) * NGRID + slon;
            float f[4];
            if (p0 + pq + 3 <= n2) {           // aligned interior fast path
                const float4 v = *(const float4*)(xrow + p0 + pq);
                f[0] = v.x; f[1] = v.y; f[2] = v.z; f[3] = v.w;
            } else {
#pragma unroll
                for (int j = 0; j < 4; ++j) {
                    const int p = p0 + pq + j;
                    f[j] = (p <= n2) ? xrow[p] : 0.f;
                }
            }
#pragma unroll
            for (int j = 0; j < 4; ++j) {
                const int p = p0 + pq + j;
                const float b = (p >= 1 && p < n2) ? xrow[nlon - p] : 0.f;
                xe[pq + j][bl] = f[j] + b;
                xo[pq + j][bl] = f[j] - b;
            }
        }
        {
            const int mq = (tid & 15) * 4;
            const int pl = tid >> 4;           // 0..15
            float4 c = {0.f, 0.f, 0.f, 0.f};
            float4 s = {0.f, 0.f, 0.f, 0.f};
            if (p0 + pl < PMAX) {
                const size_t off = ((size_t)k * PMAX + p0 + pl) * MM + m0 + mq;
                c = *(const float4*)(cosb + off);
                s = *(const float4*)(sinb + off);
            }
            *(float4*)&cs[pl][mq] = c;
            *(float4*)&ss[pl][mq] = s;
        }
        __syncthreads();

#pragma unroll
        for (int pp = 0; pp < 16; ++pp) {
            float ev[4], ov[4], cv[4], sv[4];
            *(float4*)ev = *(const float4*)&xe[pp][4 * tx];
            *(float4*)ov = *(const float4*)&xo[pp][4 * tx];
            *(float4*)cv = *(const float4*)&cs[pp][4 * ty];
            *(float4*)sv = *(const float4*)&ss[pp][4 * ty];
#pragma unroll
            for (int i = 0; i < 4; ++i)
#pragma unroll
                for (int j = 0; j < 4; ++j) {
                    accr[i][j] += ev[i] * cv[j];
                    acci[i][j] += ov[i] * sv[j];
                }
        }
        __syncthreads();
    }

#pragma unroll
    for (int j = 0; j < 4; ++j) {
        const int m = m0 + 4 * ty + j;
        const size_t base = ((size_t)m * NLAT + k) * bcc + bct + 4 * tx;
        float4 r = {accr[0][j] * TWO_PI_F, accr[1][j] * TWO_PI_F,
                    accr[2][j] * TWO_PI_F, accr[3][j] * TWO_PI_F};
        float4 s = {acci[0][j] * TWO_PI_F, acci[1][j] * TWO_PI_F,
                    acci[2][j] * TWO_PI_F, acci[3][j] * TWO_PI_F};
        *(float4*)&re_ws[base] = r;
        *(float4*)&im_ws[base] = s;
    }
}

// ---------------------------------------------------------------------------
// Stage 2 (parity-folded, 128bc x 64l, 8x4 micro) + T14 async-STAGE split:
// chunk t+1's global loads (8x interm float4 + 1x weight float4) issue into
// registers right after the first barrier of chunk t; the 16-k inner loop
// (~2600 cyc) hides the ~900-cyc HBM latency.  Round-8 counters: VALUBusy
// 35%, occupancy 11% -> latency-bound; this targets that stall directly.
// VGPR ~156 -> ~190 (no min-waves bound; spill threshold ~512 — safe).
// ---------------------------------------------------------------------------
__global__ __launch_bounds__(256) void sht_stage2(
    const float* __restrict__ ws,
    float* __restrict__ ws2,
    const float* __restrict__ weight,
    int bcc)
{
    const int m   = blockIdx.z;
    const int l0  = blockIdx.y * 64;
    const int bct = blockIdx.x * 128;
    if (l0 + 63 < m) return;                   // weight == 0 for whole tile

    const int tid = threadIdx.x;
    const int tx  = tid & 15;                  // -> bc micro (4*tx, 64+4*tx)
    const int ty  = tid >> 4;                  // -> l micro (4*ty + j)

    const int klo16 = kmin_of_m(m) & ~15;
    const int pcnt  = 96 - klo16;              // pair count, multiple of 16

    const float* __restrict__ re_ws = ws;
    const float* __restrict__ im_ws = ws + (size_t)MM * NLAT * bcc;

    __shared__ float Ar[16][128];   // even-parity source (re), m-parity pre-swapped
    __shared__ float Br[16][128];   // odd-parity  source (re)
    __shared__ float Ai[16][128];
    __shared__ float Bi[16][128];
    __shared__ float wl[16][68];    // [k][l], padded

    float accr[8][4] = {{0.f}};
    float acci[8][4] = {{0.f}};

    const bool modd = (m & 1) != 0;
    const int  srow = tid >> 5;                // 0..7 pair-row (2 passes)
    const int  scol = (tid & 31) * 4;          // bc col (float4), 0..124
    const int  wli  = tid & 63;                // weight l col 0..63
    const int  wkq  = (tid >> 6) * 4;          // weight k quad base 0,4,8,12

    float4 par[2], pbr[2], pai[2], pbi[2], pw; // prefetch registers

    auto s2_load = [&](int P0) {
#pragma unroll
        for (int pass = 0; pass < 2; ++pass) {
            const int row = srow + pass * 8;
            const size_t offa = ((size_t)m * NLAT + (P0 + row)) * bcc + bct + scol;
            const size_t offb = ((size_t)m * NLAT + (191 - P0 - row)) * bcc + bct + scol;
            par[pass] = *(const float4*)&re_ws[offa];
            pbr[pass] = *(const float4*)&re_ws[offb];
            pai[pass] = *(const float4*)&im_ws[offa];
            pbi[pass] = *(const float4*)&im_ws[offb];
        }
        pw = *(const float4*)&weight[((size_t)m * LL + l0 + wli) * NLAT + P0 + wkq];
    };

    s2_load(klo16);                            // prologue prefetch

    for (int pc = 0; pc < pcnt; pc += 16) {
        const int p0 = klo16 + pc;
        // ---- write prefetched chunk to LDS (fold + parity pre-swap) ----
#pragma unroll
        for (int pass = 0; pass < 2; ++pass) {
            const int row = srow + pass * 8;
            const float4 ar = par[pass], br = pbr[pass];
            const float4 ai = pai[pass], bi = pbi[pass];
            float4 er = {ar.x + br.x, ar.y + br.y, ar.z + br.z, ar.w + br.w};
            float4 od = {ar.x - br.x, ar.y - br.y, ar.z - br.z, ar.w - br.w};
            float4 ei = {ai.x + bi.x, ai.y + bi.y, ai.z + bi.z, ai.w + bi.w};
            float4 oi = {ai.x - bi.x, ai.y - bi.y, ai.z - bi.z, ai.w - bi.w};
            if (modd) { float4 t = er; er = od; od = t; t = ei; ei = oi; oi = t; }
            *(float4*)&Ar[row][scol] = er;
            *(float4*)&Br[row][scol] = od;
            *(float4*)&Ai[row][scol] = ei;
            *(float4*)&Bi[row][scol] = oi;
        }
        wl[wkq + 0][wli] = pw.x;
        wl[wkq + 1][wli] = pw.y;
        wl[wkq + 2][wli] = pw.z;
        wl[wkq + 3][wli] = pw.w;
        __syncthreads();

        // ---- issue next chunk's loads: latency hides under the inner loop ----
        if (pc + 16 < pcnt) s2_load(p0 + 16);

        // ---- inner 16-k FMA loop (unchanged) ----
#pragma unroll
        for (int kk = 0; kk < 16; ++kk) {
            const float4 ea = *(const float4*)&Ar[kk][4 * tx];
            const float4 eb = *(const float4*)&Ar[kk][64 + 4 * tx];
            const float4 oa = *(const float4*)&Br[kk][4 * tx];
            const float4 ob = *(const float4*)&Br[kk][64 + 4 * tx];
            const float4 fa = *(const float4*)&Ai[kk][4 * tx];
            const float4 fb = *(const float4*)&Ai[kk][64 + 4 * tx];
            const float4 ga = *(const float4*)&Bi[kk][4 * tx];
            const float4 gb = *(const float4*)&Bi[kk][64 + 4 * tx];
            const float4 wv = *(const float4*)&wl[kk][4 * ty];
            const float er8[8] = {ea.x, ea.y, ea.z, ea.w, eb.x, eb.y, eb.z, eb.w};
            const float or8[8] = {oa.x, oa.y, oa.z, oa.w, ob.x, ob.y, ob.z, ob.w};
            const float ei8[8] = {fa.x, fa.y, fa.z, fa.w, fb.x, fb.y, fb.z, fb.w};
            const float oi8[8] = {ga.x, ga.y, ga.z, ga.w, gb.x, gb.y, gb.z, gb.w};
#pragma unroll
            for (int i = 0; i < 8; ++i) {
                accr[i][0] += er8[i] * wv.x;   // j=0: (l+m) even -> A
                accr[i][1] += or8[i] * wv.y;   // j=1: odd -> B
                accr[i][2] += er8[i] * wv.z;
                accr[i][3] += or8[i] * wv.w;
                acci[i][0] += ei8[i] * wv.x;
                acci[i][1] += oi8[i] * wv.y;
                acci[i][2] += ei8[i] * wv.z;
                acci[i][3] += oi8[i] * wv.w;
            }
        }
        __syncthreads();
    }

    float* __restrict__ re2 = ws2;
    float* __restrict__ im2 = ws2 + (size_t)MM * LL * bcc;
#pragma unroll
    for (int j = 0; j < 4; ++j) {
        const int l = l0 + 4 * ty + j;
        if (l < m) continue;                   // zero region: never read
        const size_t base = ((size_t)m * LL + l) * bcc + bct;
        float4 r0 = {accr[0][j], accr[1][j], accr[2][j], accr[3][j]};
        float4 r1 = {accr[4][j], accr[5][j], accr[6][j], accr[7][j]};
        float4 i0 = {acci[0][j], acci[1][j], acci[2][j], acci[3][j]};
        float4 i1 = {acci[4][j], acci[5][j], acci[6][j], acci[7][j]};
        *(float4*)&re2[base + 4 * tx]      = r0;
        *(float4*)&re2[base + 64 + 4 * tx] = r1;
        *(float4*)&im2[base + 4 * tx]      = i0;
        *(float4*)&im2[base + 64 + 4 * tx] = i1;
    }
}

// ---------------------------------------------------------------------------
// Transpose: out[bc][l][m][2] = {re2[m][l][bc], im2[m][l][bc]}  (0 for m > l)
// UNCHANGED from round 8.  Grid: (bcc/64, 3 m-tiles of 64, 192 l).  Block 256.
// ---------------------------------------------------------------------------
__global__ __launch_bounds__(256) void sht_transpose(
    const float* __restrict__ ws2,
    float* __restrict__ out,
    int bc0, int bcc)
{
    const int l   = blockIdx.z;
    const int m0  = blockIdx.y * 64;
    const int bct = blockIdx.x * 64;
    const int tid = threadIdx.x;

    __shared__ float t2r[64][66];   // [bc][m]
    __shared__ float t2i[64][66];

    const bool anynz = (m0 <= l);
    if (anynz) {
        const float* __restrict__ re2 = ws2;
        const float* __restrict__ im2 = ws2 + (size_t)MM * LL * bcc;
        const int bl4 = (tid & 15) * 4;        // 16 lanes * float4 = 64 bc
        const int mr  = tid >> 4;              // 16 m-rows per pass
#pragma unroll
        for (int r = 0; r < 4; ++r) {
            const int row = mr + r * 16;
            const size_t off = ((size_t)(m0 + row) * LL + l) * bcc + bct + bl4;
            const float4 a = *(const float4*)&re2[off];
            const float4 b = *(const float4*)&im2[off];
            t2r[bl4 + 0][row] = a.x; t2r[bl4 + 1][row] = a.y;
            t2r[bl4 + 2][row] = a.z; t2r[bl4 + 3][row] = a.w;
            t2i[bl4 + 0][row] = b.x; t2i[bl4 + 1][row] = b.y;
            t2i[bl4 + 2][row] = b.z; t2i[bl4 + 3][row] = b.w;
        }
    }
    __syncthreads();

    const int mq  = tid & 31;                  // m pair lane (2 m per lane)
    const int bcw = tid >> 5;                  // 0..7
#pragma unroll
    for (int r = 0; r < 8; ++r) {
        const int bcl = bcw + 8 * r;
        const int bc  = bc0 + bct + bcl;
        const int m   = m0 + 2 * mq;
        float4 v = {0.f, 0.f, 0.f, 0.f};
        if (anynz) {
            const float2 rr = *(const float2*)&t2r[bcl][2 * mq];
            const float2 ii = *(const float2*)&t2i[bcl][2 * mq];
            if (m     <= l) { v.x = rr.x; v.y = ii.x; }
            if (m + 1 <= l) { v.z = rr.y; v.w = ii.y; }
        }
        const size_t o = (((size_t)bc * LL + l) * MM + m) * 2;
        *(float4*)&out[o] = v;
    }
}

// ---------------------------------------------------------------------------
extern "C" void kernel_launch(void* const* d_in, const int* in_sizes, int n_in,
                              void* d_out, int out_size, void* d_ws, size_t ws_size,
                              hipStream_t stream)
{
    const float* x      = (const float*)d_in[0];
    const float* weight = (const float*)d_in[1];
    const float* cosb   = (const float*)d_in[2];
    const float* sinb   = (const float*)d_in[3];
    const int*   ring   = (const int*)d_in[4];
    float* out = (float*)d_out;
    float* wsf = (float*)d_ws;

    // Need interm (2*M*K*bcc floats) + ws2 (2*M*L*bcc floats) per chunk.
    const size_t per_bc = 4ull * MM * NLAT * sizeof(float);
    int chunk = BC;
    while ((size_t)chunk * per_bc > ws_size && chunk > 128) chunk >>= 1;

    for (int bc0 = 0; bc0 < BC; bc0 += chunk) {
        float* ws2 = wsf + 2ull * MM * NLAT * chunk;
        dim3 grid1(chunk / 64, 3, NLAT);
        hipLaunchKernelGGL(sht_stage1, grid1, dim3(256), 0, stream,
                           x, cosb, sinb, ring, wsf, bc0, chunk);
        dim3 grid2(chunk / 128, 3, MM);
        hipLaunchKernelGGL(sht_stage2, grid2, dim3(256), 0, stream,
                           wsf, ws2, weight, chunk);
        dim3 grid3(chunk / 64, 3, LL);
        hipLaunchKernelGGL(sht_transpose, grid3, dim3(256), 0, stream,
                           ws2, out, bc0, chunk);
    }
}